// Round 10
// baseline (17.778 us; speedup 1.0000x reference)
//
#include <hip/hip_runtime.h>
#include <math.h>

#define SEQ_L 4096
#define LDS_PAD 524          // covers stride-512 prefetch over-read (max idx 4607)

typedef float v2f __attribute__((ext_vector_type(2)));
__device__ __forceinline__ v2f mk2(float a, float b) { v2f r; r.x = a; r.y = b; return r; }

// 6-step gfx9 DPP wave64 sum; result valid in lane 63. (verified R5-R9)
__device__ __forceinline__ float wave_sum_dpp(float x) {
    int t;
    t = __builtin_amdgcn_update_dpp(0, __float_as_int(x), 0x111, 0xf, 0xf, true); x += __int_as_float(t);
    t = __builtin_amdgcn_update_dpp(0, __float_as_int(x), 0x112, 0xf, 0xf, true); x += __int_as_float(t);
    t = __builtin_amdgcn_update_dpp(0, __float_as_int(x), 0x114, 0xf, 0xf, true); x += __int_as_float(t);
    t = __builtin_amdgcn_update_dpp(0, __float_as_int(x), 0x118, 0xf, 0xf, true); x += __int_as_float(t);
    t = __builtin_amdgcn_update_dpp(0, __float_as_int(x), 0x142, 0xa, 0xf, true); x += __int_as_float(t);
    t = __builtin_amdgcn_update_dpp(0, __float_as_int(x), 0x143, 0xc, 0xf, true); x += __int_as_float(t);
    return x;
}

// One group of 4 rows {b0,b0+19,b0+38,b0+57}; this wave does iterations
// t = h, h+2, ... (parity split). Packed-fp32 (v_pk_*) inner loop with
// Schraudolph exp2 (clamp-at-zero variant: underflow -> e = 0.0 exactly).
__device__ __forceinline__ void do_group_half(
    int b0, int lane, int h,
    const float* As, const float* Ws, float* Pout,
    float scaleL2, float cphi, float sphi,
    float cd, float sd, float cd2, float sd2,
    float ck1, float sk1, float ck2, float sk2, float ck3, float sk3)
{
    const float SQRT2 = 1.4142135623730951f;
    const float EXPSC = 8388608.0f;          // 2^23
    const float EXPB  = 126.956945f;         // 127 - 0.043055 (centered)
    const int i0 = b0, i1 = b0 + 19, i2 = b0 + 38, i3 = b0 + 57;
    const int c1 = i1 < SEQ_L ? i1 : SEQ_L - 1;
    const int c2 = i2 < SEQ_L ? i2 : SEQ_L - 1;
    const int c3 = i3 < SEQ_L ? i3 : SEQ_L - 1;

    const float t20 = scaleL2 * As[i0], t21 = scaleL2 * As[c1];
    const float t22 = scaleL2 * As[c2], t23 = scaleL2 * As[c3];
    const float Bs0 = (EXPB - fabsf(t20) * SQRT2) * EXPSC;
    const float Bs1 = (EXPB - fabsf(t21) * SQRT2) * EXPSC;
    const float Bs2 = (EXPB - fabsf(t22) * SQRT2) * EXPSC;
    const float Bs3 = (EXPB - fabsf(t23) * SQRT2) * EXPSC;
    const v2f T0 = mk2(t20 * EXPSC, t20 * EXPSC);
    const v2f T1 = mk2(t21 * EXPSC, t21 * EXPSC);
    const v2f T2 = mk2(t22 * EXPSC, t22 * EXPSC);
    const v2f T3 = mk2(t23 * EXPSC, t23 * EXPSC);
    const v2f B0 = mk2(Bs0, Bs0), B1 = mk2(Bs1, Bs1);
    const v2f B2 = mk2(Bs2, Bs2), B3 = mk2(Bs3, Bs3);
    const v2f z2 = mk2(0.f, 0.f);

    // shared angle state: theta = omega*((b0 - 4*lane) mod 19) - phi
    unsigned r = (unsigned)(b0 - (lane << 2) + 266) % 19u;   // 266 = 14*19
    float rev = (float)r * (1.0f / 19.0f);
    float crv = __builtin_amdgcn_cosf(rev);
    float srv = __builtin_amdgcn_sinf(rev);
    float C = fmaf(srv, sphi, crv * cphi);
    float S = fmaf(crv, -sphi, srv * cphi);
    if (h) {                               // offset by one 256-step
        float Cn = fmaf(S, sd, C * cd);
        float Sn = fmaf(S, cd, -(C * sd));
        C = Cn; S = Sn;
    }

    v2f sa0 = z2, sa1 = z2, sa2 = z2, sa3 = z2;
    v2f oa0 = z2, oa1 = z2, oa2 = z2, oa3 = z2;
    int jb = (lane << 2) + (h << 8);
    const int ncom = (b0 + 1) >> 8;
    const int T    = (c3 >> 8) + 1;        // <= 16, so consumed jb <= 4095

#define ROWP(Tm, Bm, sam, oam) { \
    v2f a01_ = __builtin_elementwise_fma(u01, Tm, Bm); \
    v2f a23_ = __builtin_elementwise_fma(u23, Tm, Bm); \
    a01_ = __builtin_elementwise_max(a01_, z2); \
    a23_ = __builtin_elementwise_max(a23_, z2); \
    v2f e01_ = mk2(__int_as_float((int)a01_.x), __int_as_float((int)a01_.y)); \
    v2f e23_ = mk2(__int_as_float((int)a23_.x), __int_as_float((int)a23_.y)); \
    sam += e01_ + e23_; \
    oam = __builtin_elementwise_fma(e01_, w01, oam); \
    oam = __builtin_elementwise_fma(e23_, w23, oam); }

#define ROWPM(Tm, Bm, sam, oam, mb01, mb23) { \
    v2f a01_ = __builtin_elementwise_fma(u01, Tm, Bm) + (mb01); \
    v2f a23_ = __builtin_elementwise_fma(u23, Tm, Bm) + (mb23); \
    a01_ = __builtin_elementwise_max(a01_, z2); \
    a23_ = __builtin_elementwise_max(a23_, z2); \
    v2f e01_ = mk2(__int_as_float((int)a01_.x), __int_as_float((int)a01_.y)); \
    v2f e23_ = mk2(__int_as_float((int)a23_.x), __int_as_float((int)a23_.y)); \
    sam += e01_ + e23_; \
    oam = __builtin_elementwise_fma(e01_, w01, oam); \
    oam = __builtin_elementwise_fma(e23_, w23, oam); }

#define ROT2() { \
    float Cn_ = fmaf(S, sd2, C * cd2); \
    float Sn_ = fmaf(S, cd2, -(C * sd2)); \
    C = Cn_; S = Sn_; }

    // register prefetch: read next tile at loop top, consume previous
    float4 av = *(const float4*)&As[jb];
    float4 wv = *(const float4*)&Ws[jb];
    int t = h;
    for (; t < ncom; t += 2) {
        float4 avn = *(const float4*)&As[jb + 512];
        float4 wvn = *(const float4*)&Ws[jb + 512];
        float C1 = fmaf(S, sk1, C * ck1);
        float C2 = fmaf(S, sk2, C * ck2);
        float C3 = fmaf(S, sk3, C * ck3);
        v2f u01 = mk2(av.x, av.y) * mk2(C,  C1);
        v2f u23 = mk2(av.z, av.w) * mk2(C2, C3);
        v2f w01 = mk2(wv.x, wv.y);
        v2f w23 = mk2(wv.z, wv.w);
        ROWP(T0, B0, sa0, oa0) ROWP(T1, B1, sa1, oa1)
        ROWP(T2, B2, sa2, oa2) ROWP(T3, B3, sa3, oa3)
        ROT2();
        av = avn; wv = wvn; jb += 512;
    }
    for (; t < T; t += 2) {
        float4 avn = *(const float4*)&As[jb + 512];
        float4 wvn = *(const float4*)&Ws[jb + 512];
        float C1 = fmaf(S, sk1, C * ck1);
        float C2 = fmaf(S, sk2, C * ck2);
        float C3 = fmaf(S, sk3, C * ck3);
        v2f u01 = mk2(av.x, av.y) * mk2(C,  C1);
        v2f u23 = mk2(av.z, av.w) * mk2(C2, C3);
        v2f w01 = mk2(wv.x, wv.y);
        v2f w23 = mk2(wv.z, wv.w);
        // causality mask as additive bias before the zero-clamp
        const float MB = -3.0e9f;
        v2f m0a = mk2(jb + 0 <= i0 ? 0.f : MB, jb + 1 <= i0 ? 0.f : MB);
        v2f m0b = mk2(jb + 2 <= i0 ? 0.f : MB, jb + 3 <= i0 ? 0.f : MB);
        v2f m1a = mk2(jb + 0 <= i1 ? 0.f : MB, jb + 1 <= i1 ? 0.f : MB);
        v2f m1b = mk2(jb + 2 <= i1 ? 0.f : MB, jb + 3 <= i1 ? 0.f : MB);
        v2f m2a = mk2(jb + 0 <= i2 ? 0.f : MB, jb + 1 <= i2 ? 0.f : MB);
        v2f m2b = mk2(jb + 2 <= i2 ? 0.f : MB, jb + 3 <= i2 ? 0.f : MB);
        v2f m3a = mk2(jb + 0 <= i3 ? 0.f : MB, jb + 1 <= i3 ? 0.f : MB);
        v2f m3b = mk2(jb + 2 <= i3 ? 0.f : MB, jb + 3 <= i3 ? 0.f : MB);
        ROWPM(T0, B0, sa0, oa0, m0a, m0b) ROWPM(T1, B1, sa1, oa1, m1a, m1b)
        ROWPM(T2, B2, sa2, oa2, m2a, m2b) ROWPM(T3, B3, sa3, oa3, m3a, m3b)
        ROT2();
        av = avn; wv = wvn; jb += 512;
    }
#undef ROWP
#undef ROWPM
#undef ROT2

    float S0 = wave_sum_dpp(sa0.x + sa0.y), O0 = wave_sum_dpp(oa0.x + oa0.y);
    float S1 = wave_sum_dpp(sa1.x + sa1.y), O1 = wave_sum_dpp(oa1.x + oa1.y);
    float S2 = wave_sum_dpp(sa2.x + sa2.y), O2 = wave_sum_dpp(oa2.x + oa2.y);
    float S3 = wave_sum_dpp(sa3.x + sa3.y), O3 = wave_sum_dpp(oa3.x + oa3.y);

    if (lane == 63) {
        Pout[0] = S0; Pout[1] = O0;
        Pout[2] = S1; Pout[3] = O1;
        Pout[4] = S2; Pout[5] = O2;
        Pout[6] = S3; Pout[7] = O3;
    }
}

__global__ __launch_bounds__(256, 4) void attn_rows_kernel(
    const float* __restrict__ x,
    const float* __restrict__ q_weight,
    const float* __restrict__ v_weight,
    const float* __restrict__ gate_weight,
    const float* __restrict__ carry_weight,
    float* __restrict__ out,
    float scaleL2,
    float cd, float sd,      // cos/sin(256*omega)
    float cd2, float sd2,    // cos/sin(512*omega)
    float ck1, float sk1, float ck2, float sk2, float ck3, float sk3)
{
    __shared__ float As[SEQ_L + LDS_PAD];
    __shared__ float Ws[SEQ_L + LDS_PAD];
    __shared__ float P[2][2][16];    // [pair_local][half][8 rows x (s,o)]

    const int tid  = threadIdx.x;
    const int lane = tid & 63;
    const int wave = tid >> 6;
    const int pl   = wave >> 1;      // pair within block: 0,1
    const int h    = wave & 1;       // parity half: 0,1
    const int bat  = blockIdx.x / 257;
    const int bb   = blockIdx.x % 257;

    const float phi = q_weight[0];
    const float vw  = v_weight[0];
    const float2* x2 = (const float2*)x + (size_t)bat * SEQ_L;
    float2* outp = (float2*)out + (size_t)bat * SEQ_L;

    const float INV2PI = 0.15915494309189535f;
    const float rphi = phi * INV2PI;
    const float cphi = __builtin_amdgcn_cosf(rphi);
    const float sphi = __builtin_amdgcn_sinf(rphi);

    const float4* x4 = (const float4*)x2;
    #pragma unroll
    for (int it = 0; it < 8; ++it) {
        int idx = tid + (it << 8);
        float4 v = x4[idx];
        int e0 = idx << 1, e1 = e0 + 1;
        float inv0 = __builtin_amdgcn_rsqf(fmaf(v.x, v.x*0.5f, fmaf(v.y, v.y*0.5f, 1e-6f)));
        float xn0a = v.x * inv0;
        As[e0] = xn0a * __builtin_amdgcn_rsqf(fmaf(xn0a, xn0a*0.5f, 1e-6f));
        Ws[e0] = v.y * inv0 * vw;
        float inv1 = __builtin_amdgcn_rsqf(fmaf(v.z, v.z*0.5f, fmaf(v.w, v.w*0.5f, 1e-6f)));
        float xn0b = v.z * inv1;
        As[e1] = xn0b * __builtin_amdgcn_rsqf(fmaf(xn0b, xn0b*0.5f, 1e-6f));
        Ws[e1] = v.w * inv1 * vw;
    }
    // zero the prefetch pad (read-only region beyond SEQ_L)
    for (int z = tid; z < LDS_PAD; z += 256) {
        As[SEQ_L + z] = 0.f;
        Ws[SEQ_L + z] = 0.f;
    }
    __syncthreads();

    const int p = bb * 2 + pl;           // pair index 0..512
    const bool active = (p < 513);
    int b0A = 0, b0B = 0;
    if (active) {
        const int m = p / 19;
        const int c = p - 19 * m;
        b0A = 76 * m + c;                // light group (<=1994)
        b0B = 4046 - b0A;                // mirror heavy group (>=2052)
        do_group_half(b0A, lane, h, As, Ws, &P[pl][h][0],
                      scaleL2, cphi, sphi, cd, sd, cd2, sd2,
                      ck1, sk1, ck2, sk2, ck3, sk3);
        do_group_half(b0B, lane, h, As, Ws, &P[pl][h][8],
                      scaleL2, cphi, sphi, cd, sd, cd2, sd2,
                      ck1, sk1, ck2, sk2, ck3, sk3);
    }
    __syncthreads();

    // combine halves + epilogue: wave h==0, 8 lanes = 8 rows of this pair
    if (active && h == 0 && lane < 8) {
        const float ga = gate_weight[0];
        const float gc = gate_weight[1];
        const float cw = carry_weight[0];
        const float LOG2E = 1.4426950408889634f;

        const int rsub = lane & 3;
        const int i = (lane < 4) ? (b0A + 19 * rsub) : (b0B + 19 * rsub);
        const int k = lane * 2;          // 0..15 within P[pl][.][16]
        if (i < SEQ_L) {
            float s = P[pl][0][k]     + P[pl][1][k];
            float o = P[pl][0][k + 1] + P[pl][1][k + 1];
            float o0 = o * __builtin_amdgcn_rcpf(s);
            float2 xv = x2[i];
            float h0 = xv.x, h1 = xv.y + o0;
            float inv = __builtin_amdgcn_rsqf(
                           fmaf(h0, h0*0.5f, fmaf(h1, h1*0.5f, 1e-6f)));
            float hn0 = h0 * inv, hn1 = h1 * inv;
            float g0 = hn0 * ga + hn1 * gc;
            float g1 = hn0 * (ga - gc * 1e-3f) + hn1 * gc;
            float sg0 = __builtin_amdgcn_rcpf(1.f + __builtin_amdgcn_exp2f(-g0 * LOG2E));
            float sg1 = __builtin_amdgcn_rcpf(1.f + __builtin_amdgcn_exp2f(-g1 * LOG2E));
            float y1 = cw * (g1 * sg1 - g0 * sg0) * hn0;
            outp[i] = make_float2(h0, h1 + y1);
        }
    }
}

extern "C" void kernel_launch(void* const* d_in, const int* in_sizes, int n_in,
                              void* d_out, int out_size, void* d_ws, size_t ws_size,
                              hipStream_t stream)
{
    const float* x  = (const float*)d_in[0];
    // d_in[1] = mask — causality handled analytically, unused
    const float* qw = (const float*)d_in[2];
    const float* vw = (const float*)d_in[3];
    const float* gw = (const float*)d_in[4];
    const float* cw = (const float*)d_in[5];
    float* out = (float*)d_out;

    const double omega = 2.0 * M_PI / 19.0;
    const double amp   = log(10.0) / (cos(omega * 0.3) - cos(omega * 0.7));
    const double qkns2 = amp / sqrt(2.0);               // QK_NORM_SCALE^2
    const double scale = pow(2.0, -0.5) * qkns2;        // HEAD_DIM^-0.5 * QK_NORM_SCALE^2
    const double L2E   = 1.4426950408889634074;
    const double d1    = 256.0 * omega;
    const double d2    = 512.0 * omega;

    attn_rows_kernel<<<dim3(4 * 257), dim3(256), 0, stream>>>(
        x, qw, vw, gw, cw, out,
        (float)(scale * L2E),
        (float)cos(d1),          (float)sin(d1),
        (float)cos(d2),          (float)sin(d2),
        (float)cos(omega),       (float)sin(omega),
        (float)cos(2.0 * omega), (float)sin(2.0 * omega),
        (float)cos(3.0 * omega), (float)sin(3.0 * omega));
}